// Round 8
// baseline (271.794 us; speedup 1.0000x reference)
//
#include <hip/hip_runtime.h>
#include <hip/hip_bf16.h>
#include <math.h>

#define MDIM 8192
#define NDIM 4096
#define KDIM 128
#define NB 1792          // persistent blocks
#define TILES_PER_BLK 16 // 28672 tiles total = NB * 16

typedef __bf16 bf16x8 __attribute__((ext_vector_type(8)));
typedef float f32x4 __attribute__((ext_vector_type(4)));

__device__ __forceinline__ unsigned short f32_to_bf16_rne(float f) {
  unsigned int u = __float_as_uint(f);
  u += 0x7fffu + ((u >> 16) & 1u);
  return (unsigned short)(u >> 16);
}

// Convert f32 -> bf16 (vectorized), and compute sum of squares (for ||U||_F, ||V||_F)
__global__ void convert_kernel(const float* __restrict__ X, unsigned short* __restrict__ Xb,
                               double* __restrict__ partial, int n4) {
  int tid = blockIdx.x * blockDim.x + threadIdx.x;
  int stride = gridDim.x * blockDim.x;
  float s = 0.f;
  const float4* X4 = (const float4*)X;
  ushort4* Xb4 = (ushort4*)Xb;
  for (int i = tid; i < n4; i += stride) {
    float4 v = X4[i];
    s += v.x * v.x + v.y * v.y + v.z * v.z + v.w * v.w;
    ushort4 p;
    p.x = f32_to_bf16_rne(v.x);
    p.y = f32_to_bf16_rne(v.y);
    p.z = f32_to_bf16_rne(v.z);
    p.w = f32_to_bf16_rne(v.w);
    Xb4[i] = p;
  }
  for (int off = 32; off > 0; off >>= 1) s += __shfl_down(s, off, 64);
  __shared__ float sw[4];
  int lane = threadIdx.x & 63, wid = threadIdx.x >> 6;
  if (lane == 0) sw[wid] = s;
  __syncthreads();
  if (threadIdx.x == 0) partial[blockIdx.x] = (double)(sw[0] + sw[1] + sw[2] + sw[3]);
}

// Flat 64x64-tile space over all three products:
//   t in [0, 8192):       recon  (U V^T vs A),   128 x 64 tiles, ldT=4096
//   t in [8192, 24576):   S_m    (U U^T vs S_m), 128 x 128 tiles, ldT=8192
//   t in [24576, 28672):  S_d    (V V^T vs S_d),  64 x 64 tiles, ldT=4096
struct TileCtx {
  const unsigned short* Xr;  // lane's X fragment base
  const unsigned short* Yr;  // lane's Y fragment base
  const f32x4* Tp;           // lane's T base (float4 units)
  int ld4_16;                // 16 * (ldT/4)
  int seg;
};

__device__ __forceinline__ TileCtx tile_setup(
    int t, int wr, int wc, int l15, int lg,
    const unsigned short* Ub, const unsigned short* Vb,
    const float* A, const float* Sm, const float* Sd) {
  TileCtx cx;
  const unsigned short* Xb;
  const unsigned short* Yb;
  const float* T;
  int r, c, ld;
  if (t < 8192) {
    cx.seg = 0; r = t >> 6; c = t & 63; Xb = Ub; Yb = Vb; T = A; ld = NDIM;
  } else if (t < 24576) {
    int u = t - 8192; cx.seg = 1; r = u >> 7; c = u & 127; Xb = Ub; Yb = Ub; T = Sm; ld = MDIM;
  } else {
    int u = t - 24576; cx.seg = 2; r = u >> 6; c = u & 63; Xb = Vb; Yb = Vb; T = Sd; ld = NDIM;
  }
  const int prow0 = r * 64 + wr * 32;
  const int pcol0 = c * 64 + wc * 32;
  cx.Xr = Xb + (size_t)(prow0 + l15) * KDIM + lg * 8;
  cx.Yr = Yb + (size_t)(pcol0 + l15) * KDIM + lg * 8;
  const int ld4 = ld >> 2;
  cx.Tp = (const f32x4*)T + (size_t)(prow0 + l15) * ld4 + (pcol0 >> 2) + lg;
  cx.ld4_16 = ld4 * 16;
  return cx;
}

// Persistent fused kernel: 1792 blocks x 16 tiles, cross-tile software pipeline.
// Per tile: 16 frag loads (L2-resident panels) + 4 T float4 loads, registers only.
// Steady state: MFMA(i) -> issue frags(i+1) + T(i+1) -> compare(i) vs tpre buf.
// T double-buffered in NAMED register arrays (tA/tB); compiler emits counted
// vmcnt per register so T(i+1) stays in flight across compare(i) and MFMA(i+1).
// No barriers in the loop; block-level reduce once at the end.
__global__ __launch_bounds__(256, 3) void fused_persistent(
    const unsigned short* __restrict__ Ub,  // [M][128] bf16 bits
    const unsigned short* __restrict__ Vb,  // [N][128] bf16 bits
    const float* __restrict__ A,
    const float* __restrict__ S_m,
    const float* __restrict__ S_d,
    double* __restrict__ partial) {        // [3*NB]
  const int b = blockIdx.x;
  const int tid = threadIdx.x;
  const int lane = tid & 63;
  const int wid = tid >> 6;
  const int wr = wid >> 1, wc = wid & 1;
  const int l15 = lane & 15;
  const int lg = lane >> 4;

  float s0 = 0.f, s1 = 0.f, s2 = 0.f;

  int t = b * TILES_PER_BLK;
  const int tend = t + TILES_PER_BLK;

  TileCtx cx = tile_setup(t, wr, wc, l15, lg, Ub, Vb, A, S_m, S_d);
  int seg_cur = cx.seg;

  bf16x8 x[2][4], y[2][4];  // [row/col-subtile][kk]
#pragma unroll
  for (int q = 0; q < 2; ++q)
#pragma unroll
    for (int kk = 0; kk < 4; ++kk) {
      x[q][kk] = *(const bf16x8*)(cx.Xr + (size_t)q * 16 * KDIM + kk * 32);
      y[q][kk] = *(const bf16x8*)(cx.Yr + (size_t)q * 16 * KDIM + kk * 32);
    }
  f32x4 tA[2][2], tB[2][2];
#pragma unroll
  for (int q = 0; q < 2; ++q)
#pragma unroll
    for (int p = 0; p < 2; ++p)
      tA[q][p] = cx.Tp[(size_t)q * cx.ld4_16 + p * 4];

#define HALF_STEP(TC, TN)                                                        \
  {                                                                              \
    f32x4 acc[2][2] = {};                                                        \
    _Pragma("unroll") for (int kk = 0; kk < 4; ++kk)                             \
      _Pragma("unroll") for (int p = 0; p < 2; ++p)                              \
        _Pragma("unroll") for (int q = 0; q < 2; ++q)                            \
          acc[p][q] = __builtin_amdgcn_mfma_f32_16x16x32_bf16(                   \
              y[p][kk], x[q][kk], acc[p][q], 0, 0, 0);                           \
    const int seg_c = seg_cur;                                                   \
    ++t;                                                                         \
    if (t < tend) {                                                              \
      cx = tile_setup(t, wr, wc, l15, lg, Ub, Vb, A, S_m, S_d);                  \
      seg_cur = cx.seg;                                                          \
      _Pragma("unroll") for (int q = 0; q < 2; ++q)                              \
        _Pragma("unroll") for (int kk = 0; kk < 4; ++kk) {                       \
          x[q][kk] = *(const bf16x8*)(cx.Xr + (size_t)q * 16 * KDIM + kk * 32);  \
          y[q][kk] = *(const bf16x8*)(cx.Yr + (size_t)q * 16 * KDIM + kk * 32);  \
        }                                                                        \
      _Pragma("unroll") for (int q = 0; q < 2; ++q)                              \
        _Pragma("unroll") for (int p = 0; p < 2; ++p)                            \
          TN[q][p] = cx.Tp[(size_t)q * cx.ld4_16 + p * 4];                       \
    }                                                                            \
    float ts = 0.f;                                                              \
    _Pragma("unroll") for (int q = 0; q < 2; ++q)                                \
      _Pragma("unroll") for (int p = 0; p < 2; ++p) {                            \
        const f32x4 d = acc[p][q] - TC[q][p];                                    \
        ts += d[0] * d[0] + d[1] * d[1] + d[2] * d[2] + d[3] * d[3];             \
      }                                                                          \
    if (seg_c == 0) s0 += ts; else if (seg_c == 1) s1 += ts; else s2 += ts;      \
  }

  for (int i = 0; i < TILES_PER_BLK / 2; ++i) {
    HALF_STEP(tA, tB);
    HALF_STEP(tB, tA);
  }
#undef HALF_STEP

  // block reduction (deterministic)
  for (int off = 32; off > 0; off >>= 1) {
    s0 += __shfl_down(s0, off, 64);
    s1 += __shfl_down(s1, off, 64);
    s2 += __shfl_down(s2, off, 64);
  }
  __shared__ float red[3][4];
  if (lane == 0) { red[0][wid] = s0; red[1][wid] = s1; red[2][wid] = s2; }
  __syncthreads();
  if (tid == 0) {
    partial[b]          = (double)(red[0][0] + red[0][1] + red[0][2] + red[0][3]);
    partial[NB + b]     = (double)(red[1][0] + red[1][1] + red[1][2] + red[1][3]);
    partial[2 * NB + b] = (double)(red[2][0] + red[2][1] + red[2][2] + red[2][3]);
  }
}

// Deterministic final reduction of all partial arrays + scalar combine.
__global__ void finalize_kernel(const double* __restrict__ pr, int nr,
                                const double* __restrict__ psm, int nsm,
                                const double* __restrict__ psd, int nsd,
                                const double* __restrict__ pu, int nu,
                                const double* __restrict__ pv, int nv,
                                float* __restrict__ out) {
  __shared__ double sh[256];
  double sums[5];
  const double* ps[5] = {pr, psm, psd, pu, pv};
  int ns[5] = {nr, nsm, nsd, nu, nv};
  for (int q = 0; q < 5; ++q) {
    double s = 0.0;
    for (int i = threadIdx.x; i < ns[q]; i += 256) s += ps[q][i];
    sh[threadIdx.x] = s;
    __syncthreads();
    for (int k = 128; k > 0; k >>= 1) {
      if (threadIdx.x < k) sh[threadIdx.x] += sh[threadIdx.x + k];
      __syncthreads();
    }
    sums[q] = sh[0];
    __syncthreads();
  }
  if (threadIdx.x == 0) {
    double recon = sums[0] / ((double)MDIM * (double)NDIM);
    double res = recon + 0.01 * (sqrt(sums[3]) + sqrt(sums[4]) + sqrt(sums[1]) + sqrt(sums[2]));
    out[0] = (float)res;
  }
}

extern "C" void kernel_launch(void* const* d_in, const int* in_sizes, int n_in,
                              void* d_out, int out_size, void* d_ws, size_t ws_size,
                              hipStream_t stream) {
  const float* A   = (const float*)d_in[0];  // [M][N]
  const float* S_m = (const float*)d_in[1];  // [M][M]
  const float* S_d = (const float*)d_in[2];  // [N][N]
  const float* U   = (const float*)d_in[3];  // [M][K]
  const float* V   = (const float*)d_in[4];  // [N][K]

  char* ws = (char*)d_ws;
  unsigned short* Ub = (unsigned short*)ws;                             // 2 MB
  unsigned short* Vb = (unsigned short*)(ws + (size_t)2 * 1024 * 1024); // 1 MB
  double* pd = (double*)(ws + (size_t)3 * 1024 * 1024);
  double* p_all = pd;              // 3*NB: [0,NB) recon | [NB,2NB) S_m | [2NB,3NB) S_d
  double* p_u   = p_all + 3 * NB;  // 256
  double* p_v   = p_u + 256;       // 256

  convert_kernel<<<256, 256, 0, stream>>>(U, Ub, p_u, MDIM * KDIM / 4);
  convert_kernel<<<256, 256, 0, stream>>>(V, Vb, p_v, NDIM * KDIM / 4);

  fused_persistent<<<NB, 256, 0, stream>>>(Ub, Vb, A, S_m, S_d, p_all);

  finalize_kernel<<<1, 256, 0, stream>>>(p_all, NB, p_all + NB, NB, p_all + 2 * NB, NB,
                                         p_u, 256, p_v, 256, (float*)d_out);
}

// Round 9
// 111.258 us; speedup vs baseline: 2.4429x; 2.4429x over previous
//
#include <hip/hip_runtime.h>
#include <hip/hip_bf16.h>
#include <math.h>

#define MDIM 8192
#define NDIM 4096
#define KDIM 128

typedef __bf16 bf16x8 __attribute__((ext_vector_type(8)));
typedef float f32x4 __attribute__((ext_vector_type(4)));

__device__ __forceinline__ unsigned short f32_to_bf16_rne(float f) {
  unsigned int u = __float_as_uint(f);
  u += 0x7fffu + ((u >> 16) & 1u);
  return (unsigned short)(u >> 16);
}

// Convert f32 -> bf16 (vectorized), and compute sum of squares (for ||U||_F, ||V||_F)
__global__ void convert_kernel(const float* __restrict__ X, unsigned short* __restrict__ Xb,
                               double* __restrict__ partial, int n4) {
  int tid = blockIdx.x * blockDim.x + threadIdx.x;
  int stride = gridDim.x * blockDim.x;
  float s = 0.f;
  const float4* X4 = (const float4*)X;
  ushort4* Xb4 = (ushort4*)Xb;
  for (int i = tid; i < n4; i += stride) {
    float4 v = X4[i];
    s += v.x * v.x + v.y * v.y + v.z * v.z + v.w * v.w;
    ushort4 p;
    p.x = f32_to_bf16_rne(v.x);
    p.y = f32_to_bf16_rne(v.y);
    p.z = f32_to_bf16_rne(v.z);
    p.w = f32_to_bf16_rne(v.w);
    Xb4[i] = p;
  }
  for (int off = 32; off > 0; off >>= 1) s += __shfl_down(s, off, 64);
  __shared__ float sw[4];
  int lane = threadIdx.x & 63, wid = threadIdx.x >> 6;
  if (lane == 0) sw[wid] = s;
  __syncthreads();
  if (threadIdx.x == 0) partial[blockIdx.x] = (double)(sw[0] + sw[1] + sw[2] + sw[3]);
}

// ALL THREE fused products, one 128x128 tile per block (merged 1D grid as R7):
//   g in [0,2048):      (Ub Vb^T vs A  )  32 block-cols, ldT=4096
//   g in [2048,6144):   (Ub Ub^T vs S_m)  64 block-cols, ldT=8192
//   g in [6144,7168):   (Vb Vb^T vs S_d)  32 block-cols, ldT=4096
//
// R8 diagnosis: every prior variant issued 16-segment 64B gathers (fragment-
// layout addressing) -> per-CU outstanding-request queue full of half-lines ->
// ~1.3 TB/s ceiling regardless of structure. This version makes EVERY global
// access wave-contiguous full 128B lines and moves MFMA operands off vmcnt:
//  1) X/Y panels staged to LDS via global_load_lds (1KB/instr, linear dest,
//     source chunk-XOR-swizzled so frag ds_read_b128 is bank-uniform).
//  2) T tile -> registers, wave-contiguous (8 full lines/instr), issued after
//     panels; counted s_waitcnt vmcnt(16) + raw s_barrier leaves all 16 T
//     loads in flight across the whole MFMA phase (frag reads are lgkmcnt).
//  3) P redistributed through the same 64KB LDS (panels dead after MFMA);
//     swizzled f32x4 writes, wave-contiguous reads, compare vs register T.
__global__ __launch_bounds__(256, 2) void fused_all(
    const unsigned short* __restrict__ Ub,  // [M][128] bf16 bits
    const unsigned short* __restrict__ Vb,  // [N][128] bf16 bits
    const float* __restrict__ A,
    const float* __restrict__ S_m,
    const float* __restrict__ S_d,
    double* __restrict__ partial) {
  __shared__ float LDSf[16384];  // 64KB: panels (X:0-32KB, Y:32-64KB) then P
  char* LDSc = (char*)LDSf;

  const int g = blockIdx.x;
  const unsigned short* Xb;
  const unsigned short* Yb;
  const float* T;
  int ldT, v, gc;
  if (g < 2048) {
    Xb = Ub; Yb = Vb; T = A; ldT = NDIM; v = g; gc = 32;
  } else if (g < 6144) {
    Xb = Ub; Yb = Ub; T = S_m; ldT = MDIM; v = g - 2048; gc = 64;
  } else {
    Xb = Vb; Yb = Vb; T = S_d; ldT = NDIM; v = g - 6144; gc = 32;
  }
  const int r_blk = v / gc;
  const int c_blk = v - r_blk * gc;
  const int brow = r_blk * 128, bcol = c_blk * 128;

  const int tid = threadIdx.x;
  const int lane = tid & 63;
  const int wid = tid >> 6;
  const int wr = wid >> 1, wc = wid & 1;
  const int l15 = lane & 15;
  const int lg = lane >> 4;

  // ---- 1) stage X,Y panels to LDS: wave-linear dest, chunk-swizzled source ----
  // LDS[row][chunk j] = G[row][j ^ (row&7)]  (16B chunks, 16 per 256B row)
  {
    const int ro = lane >> 4;       // row within 4-row group
    const int j = lane & 15;        // 16B chunk within row
#pragma unroll
    for (int i = 0; i < 8; ++i) {
      const int rl = wid * 32 + i * 4 + ro;
      const unsigned short* gp = Xb + (size_t)(brow + rl) * KDIM + ((j ^ (rl & 7)) << 3);
      __builtin_amdgcn_global_load_lds(
          (const __attribute__((address_space(1))) void*)gp,
          (__attribute__((address_space(3))) void*)(LDSc + (wid * 32 + i * 4) * 256), 16, 0, 0);
    }
#pragma unroll
    for (int i = 0; i < 8; ++i) {
      const int rl = wid * 32 + i * 4 + ro;
      const unsigned short* gp = Yb + (size_t)(bcol + rl) * KDIM + ((j ^ (rl & 7)) << 3);
      __builtin_amdgcn_global_load_lds(
          (const __attribute__((address_space(1))) void*)gp,
          (__attribute__((address_space(3))) void*)(LDSc + 32768 + (wid * 32 + i * 4) * 256), 16, 0, 0);
    }
  }
  __builtin_amdgcn_sched_barrier(0);

  // ---- 2) T tile -> registers, wave-contiguous (2 rows x 512B per instr) ----
  const f32x4* Tb = (const f32x4*)T + (size_t)brow * (ldT >> 2) + (bcol >> 2);
  const int ldT4 = ldT >> 2;
  const int tr = tid >> 5, tc = tid & 31;  // base row scatter within tile
  f32x4 t[16];
#pragma unroll
  for (int it = 0; it < 16; ++it)
    t[it] = Tb[(size_t)(it * 8 + tr) * ldT4 + tc];
  __builtin_amdgcn_sched_barrier(0);

  // ---- panels done (16 T loads still in flight), all waves synced ----
  asm volatile("s_waitcnt vmcnt(16)" ::: "memory");
  __builtin_amdgcn_sched_barrier(0);
  __builtin_amdgcn_s_barrier();

  // ---- 3) MFMA phase: operands from LDS (lgkmcnt only — T never drained) ----
  f32x4 acc[4][4] = {};  // acc[p][q][reg] = P[wr*64+q*16+l15][wc*64+p*16+lg*4+reg]
#pragma unroll
  for (int kk = 0; kk < 4; ++kk) {
    const int c = kk * 4 + lg;  // 16B chunk within row
    bf16x8 y[4], x[4];
#pragma unroll
    for (int p = 0; p < 4; ++p) {
      const int rl = wc * 64 + p * 16 + l15;
      y[p] = *(const bf16x8*)(LDSc + 32768 + rl * 256 + ((c ^ (rl & 7)) << 4));
    }
#pragma unroll
    for (int q = 0; q < 4; ++q) {
      const int rl = wr * 64 + q * 16 + l15;
      x[q] = *(const bf16x8*)(LDSc + rl * 256 + ((c ^ (rl & 7)) << 4));
    }
#pragma unroll
    for (int p = 0; p < 4; ++p)
#pragma unroll
      for (int q = 0; q < 4; ++q)
        acc[p][q] = __builtin_amdgcn_mfma_f32_16x16x32_bf16(y[p], x[q], acc[p][q], 0, 0, 0);
  }

  // ---- 4) panels dead; overlay P into the same LDS (swizzled f32x4) ----
  __syncthreads();
#pragma unroll
  for (int q = 0; q < 4; ++q) {
    const int rp = wr * 64 + q * 16 + l15;
#pragma unroll
    for (int p = 0; p < 4; ++p) {
      const int cw = wc * 16 + p * 4 + lg;  // 16B chunk within 512B row
      *(f32x4*)(LDSc + rp * 512 + ((cw ^ (rp & 7)) << 4)) = acc[p][q];
    }
  }
  __syncthreads();

  // ---- 5) compare: wave-contiguous LDS reads vs register T ----
  float s = 0.f;
#pragma unroll
  for (int it = 0; it < 16; ++it) {
    const int r = it * 8 + tr;
    const f32x4 pv = *(const f32x4*)(LDSc + r * 512 + ((tc ^ (r & 7)) << 4));
    const f32x4 d = pv - t[it];
    s += d[0] * d[0] + d[1] * d[1] + d[2] * d[2] + d[3] * d[3];
  }

  // deterministic block reduction
  for (int off = 32; off > 0; off >>= 1) s += __shfl_down(s, off, 64);
  __shared__ float swred[4];
  if (lane == 0) swred[wid] = s;
  __syncthreads();
  if (tid == 0)
    partial[g] = (double)(swred[0] + swred[1] + swred[2] + swred[3]);
}

// Deterministic final reduction of all partial arrays + scalar combine.
__global__ void finalize_kernel(const double* __restrict__ pr, int nr,
                                const double* __restrict__ psm, int nsm,
                                const double* __restrict__ psd, int nsd,
                                const double* __restrict__ pu, int nu,
                                const double* __restrict__ pv, int nv,
                                float* __restrict__ out) {
  __shared__ double sh[256];
  double sums[5];
  const double* ps[5] = {pr, psm, psd, pu, pv};
  int ns[5] = {nr, nsm, nsd, nu, nv};
  for (int q = 0; q < 5; ++q) {
    double s = 0.0;
    for (int i = threadIdx.x; i < ns[q]; i += 256) s += ps[q][i];
    sh[threadIdx.x] = s;
    __syncthreads();
    for (int k = 128; k > 0; k >>= 1) {
      if (threadIdx.x < k) sh[threadIdx.x] += sh[threadIdx.x + k];
      __syncthreads();
    }
    sums[q] = sh[0];
    __syncthreads();
  }
  if (threadIdx.x == 0) {
    double recon = sums[0] / ((double)MDIM * (double)NDIM);
    double res = recon + 0.01 * (sqrt(sums[3]) + sqrt(sums[4]) + sqrt(sums[1]) + sqrt(sums[2]));
    out[0] = (float)res;
  }
}

extern "C" void kernel_launch(void* const* d_in, const int* in_sizes, int n_in,
                              void* d_out, int out_size, void* d_ws, size_t ws_size,
                              hipStream_t stream) {
  const float* A   = (const float*)d_in[0];  // [M][N]
  const float* S_m = (const float*)d_in[1];  // [M][M]
  const float* S_d = (const float*)d_in[2];  // [N][N]
  const float* U   = (const float*)d_in[3];  // [M][K]
  const float* V   = (const float*)d_in[4];  // [N][K]

  char* ws = (char*)d_ws;
  unsigned short* Ub = (unsigned short*)ws;                             // 2 MB
  unsigned short* Vb = (unsigned short*)(ws + (size_t)2 * 1024 * 1024); // 1 MB
  double* pd = (double*)(ws + (size_t)3 * 1024 * 1024);
  double* p_all = pd;            // 7168: [0,2048) recon | [2048,6144) S_m | [6144,7168) S_d
  double* p_u   = p_all + 7168;  // 256
  double* p_v   = p_u + 256;     // 256

  convert_kernel<<<256, 256, 0, stream>>>(U, Ub, p_u, MDIM * KDIM / 4);
  convert_kernel<<<256, 256, 0, stream>>>(V, Vb, p_v, NDIM * KDIM / 4);

  fused_all<<<7168, 256, 0, stream>>>(Ub, Vb, A, S_m, S_d, p_all);

  finalize_kernel<<<1, 256, 0, stream>>>(p_all, 2048, p_all + 2048, 4096, p_all + 6144, 1024,
                                         p_u, 256, p_v, 256, (float*)d_out);
}